// Round 13
// baseline (322.627 us; speedup 1.0000x reference)
//
#include <hip/hip_runtime.h>
#include <stdint.h>

// int8-quantized GEMM: out[m,n] = (sum_k x[m,k]*w[n,k]) * x_scale * w_scale, fp32.
// M=64, K=4096, N=14336. Inputs materialized as int32 -> weights 235 MB/call.
//
// R5-R12: seven levers (access shape x3, occupancy x2, DMA vs VGPR, pipeline
// depth, NT policy) ALL neutral at gemm ~100 us (~2.4-2.7 TB/s read).
// R11 re-read: rep1 was NOT L3-served (150/235 MB re-fetched from HBM) -> the
// probe never excluded DRAM-side limits. Never-varied dimension: per-stream
// burst length (always 1 KB/step/row; ~12k interleaved streams -> row thrash).
// R13: whole-row sequential bursts. Each wave streams its 2 rows as 16
// back-to-back 1 KB loads (16 KB contiguous in flight), packs in-register,
// ds_writes a whole-tile 64 KB LDS buffer (XOR swizzle, <=2-way banks both
// sides). One barrier, then LDS/MFMA compute. 2 blocks/CU overlap phases.
#define KDIM 4096
#define NDIM 14336
#define MT_BYTES 65536            // xf bytes per m-tile (64 chunks * 1 KB)

typedef int v4i __attribute__((ext_vector_type(4)));

__device__ __forceinline__ int pack4(int w0, int w1, int w2, int w3) {
    int t01 = __builtin_amdgcn_perm(w1, w0, 0x00000400u);
    int t23 = __builtin_amdgcn_perm(w3, w2, 0x00000400u);
    return  __builtin_amdgcn_perm(t23, t01, 0x05040100u);
}

// Pack x [64,4096] int32 -> int8 in MFMA-fragment order (validated R8-R12):
// xf[mtile][chunk c][lane l][16B] = x[mtile*16+(l&15)][c*64+(l>>4)*16 ..+16].
__global__ void pack_x_frag_kernel(const int* __restrict__ xi, int8_t* __restrict__ xf) {
    const int o   = blockIdx.x * 256 + threadIdx.x;  // 0..16383
    const int mt  = o >> 12;
    const int rem = o & 4095;
    const int c   = rem >> 6;
    const int l   = rem & 63;
    const int r   = l & 15;
    const int kg  = l >> 4;
    const int* src = xi + ((size_t)(mt * 16 + r) * KDIM + c * 64 + kg * 16);
    v4i d;
    #pragma unroll
    for (int e = 0; e < 4; ++e) {
        v4i v = *(const v4i*)(src + e * 4);
        d[e] = pack4(v[0], v[1], v[2], v[3]);
    }
    *(v4i*)(xf + (size_t)o * 16) = d;
}

// Block = 8 waves (512 thr), one 16-wide N tile (16 weight rows).
// Phase A: wave w streams rows 2w, 2w+1 -- per row, 16 back-to-back 1 KB
//   contiguous loads (deep vmcnt queue, one sequential stream per wave),
//   in-register pack4, swizzled ds_write into the 64 KB packed tile.
//   Swizzle: original 16B-granule G of row R stored at granule
//   (G&~15)|((G&15)^R) -> writer 2-way banks, reader 2-way banks (free).
// Phase B: wave w consumes chunks c=cc*4+(w&3) for m-tiles 2g,2g+1 (g=w>>2):
//   swizzled ds_read_b128 -> pack is NOT needed (already packed) -> 2 MFMA.
// Epilogue: R9/R11-validated cross-wave split-K reduce.
// Fragment spec (HW-validated R2..R12): row/col = lane&15, k = (lane>>4)*16+j.
__global__ __launch_bounds__(512, 4) void gemm_i8_kernel(
    const int8_t* __restrict__ xf,
    const float*  __restrict__ xs,
    const int*    __restrict__ wq32,
    const float*  __restrict__ wscale,
    float*        __restrict__ out)
{
    __shared__ int8_t lds[65536];   // packed 16-row tile; epilogue aliases 16 KB

    const int tid  = threadIdx.x;
    const int wave = tid >> 6;     // 0..7
    const int lane = tid & 63;
    const int r    = lane & 15;
    const int kg   = lane >> 4;
    const int g    = wave >> 2;    // m-group: m-tiles 2g, 2g+1
    const int cw   = wave & 3;     // chunk class
    const int n0   = blockIdx.x * 16;

    // ---- Phase A: stream 2 whole rows sequentially ----
    #pragma unroll
    for (int j = 0; j < 2; ++j) {
        const int R = 2 * wave + j;
        const int* src = wq32 + (size_t)(n0 + R) * KDIM + lane * 4;

        v4i gw[16];
        #pragma unroll
        for (int seg = 0; seg < 16; ++seg)
            gw[seg] = *(const v4i*)(src + seg * 256);   // 16 KB contiguous, all in flight

        #pragma unroll
        for (int seg = 0; seg < 16; ++seg) {
            const int pk = pack4(gw[seg][0], gw[seg][1], gw[seg][2], gw[seg][3]);
            // original granule G = seg*16 + (lane>>2); low4 = lane>>2.
            const int gsw = ((lane >> 2) ^ R) & 15;      // swizzled low-4 of granule
            const int dst = R * 4096 + ((seg * 16 + gsw) << 4) + ((lane & 3) << 2);
            *(int*)&lds[dst] = pk;
        }
    }

    __syncthreads();   // whole packed tile visible

    // ---- Phase B: 16 chunks per wave, fragment reads from LDS ----
    const int8_t* ap = xf + lane * 16;

    v4i acc[2];
    acc[0] = (v4i){0, 0, 0, 0};
    acc[1] = (v4i){0, 0, 0, 0};

    // Prefetch chunk cw's A-fragments.
    v4i ax[2];
    #pragma unroll
    for (int t = 0; t < 2; ++t)
        ax[t] = *(const v4i*)(ap + (size_t)(2 * g + t) * MT_BYTES + (size_t)cw * 1024);

    #pragma unroll
    for (int cc = 0; cc < 16; ++cc) {
        const int c = cc * 4 + cw;

        // Prefetch next chunk's A-fragments (L2-hot) during this chunk's math.
        v4i axn[2];
        if (cc + 1 < 16) {
            const int cnext = (cc + 1) * 4 + cw;
            #pragma unroll
            for (int t = 0; t < 2; ++t)
                axn[t] = *(const v4i*)(ap + (size_t)(2 * g + t) * MT_BYTES
                                          + (size_t)cnext * 1024);
        }

        // B-fragment: row r, original granule gi = c*4+kg, swizzled low-4.
        const int gi = c * 4 + kg;
        const int gs = (gi & ~15) | ((gi & 15) ^ r);
        v4i b = *(const v4i*)&lds[r * 4096 + (gs << 4)];

        acc[0] = __builtin_amdgcn_mfma_i32_16x16x64_i8(ax[0], b, acc[0], 0, 0, 0);
        acc[1] = __builtin_amdgcn_mfma_i32_16x16x64_i8(ax[1], b, acc[1], 0, 0, 0);

        if (cc + 1 < 16) {
            ax[0] = axn[0];
            ax[1] = axn[1];
        }
    }

    // ---- Epilogue: cross-wave split-K reduce (validated R9/R11/R12) ----
    __syncthreads();
    int (*red)[2][256] = (int (*)[2][256])&lds[0];
    ((v4i*)red[wave][0])[lane] = acc[0];
    ((v4i*)red[wave][1])[lane] = acc[1];
    __syncthreads();

    if (wave < 4) {
        const int mt = wave;            // m-tile index 0..3
        const int gg = mt >> 1;
        const int tl = mt & 1;
        v4i t0 = ((v4i*)red[gg * 4 + 0][tl])[lane];
        v4i t1 = ((v4i*)red[gg * 4 + 1][tl])[lane];
        v4i t2 = ((v4i*)red[gg * 4 + 2][tl])[lane];
        v4i t3 = ((v4i*)red[gg * 4 + 3][tl])[lane];
        v4i tot = t0 + t1 + t2 + t3;

        // C/D layout (HW-validated R2): col = lane&15, row = (lane>>4)*4 + reg.
        const float scale = xs[0] * wscale[0];
        const int n = n0 + r;
        const int mbase = mt * 16 + kg * 4;
        #pragma unroll
        for (int i = 0; i < 4; ++i)
            out[(size_t)(mbase + i) * NDIM + n] = scale * (float)tot[i];
    }
}

extern "C" void kernel_launch(void* const* d_in, const int* in_sizes, int n_in,
                              void* d_out, int out_size, void* d_ws, size_t ws_size,
                              hipStream_t stream) {
    const int*   xq32   = (const int*)d_in[0];
    const float* xs     = (const float*)d_in[1];
    const int*   wq32   = (const int*)d_in[2];
    const float* wscale = (const float*)d_in[3];
    float* out = (float*)d_out;

    int8_t* xf = (int8_t*)d_ws;  // 256 KB fragment-ordered packed x

    pack_x_frag_kernel<<<64, 256, 0, stream>>>(xq32, xf);

    const int nblocks = NDIM / 16;  // 896
    gemm_i8_kernel<<<nblocks, 512, 0, stream>>>(xf, xs, wq32, wscale, out);
}

// Round 14
// 310.375 us; speedup vs baseline: 1.0395x; 1.0395x over previous
//
#include <hip/hip_runtime.h>
#include <stdint.h>

// int8-quantized GEMM: out[m,n] = (sum_k x[m,k]*w[n,k]) * x_scale * w_scale, fp32.
// M=64, K=4096, N=14336. Inputs materialized as int32 -> weights 235 MB/call.
//
// R5-R13: eight levers (access shape x4, occupancy x2, DMA vs VGPR, pipeline
// depth, NT-on-DMA-aux, burst length) ALL neutral: gemm ~102 us (~2.6 TB/s
// read). Same-call harness dispatches show writes at 6.7 TB/s and copy-read at
// ~3.1 TB/s. Hypothesis consistent with ALL data incl. the 163 MB TCC-WRITE
// anomaly: memory-side L3 (Infinity Cache) INSERTION of the once-read stream
// caps demand reads at ~2.6 TB/s. Last untried lever: true non-temporal
// VGPR loads (__builtin_nontemporal_load) on the weight stream -- R12 only
// set an aux bit on the LDS-DMA path (possibly ignored); R13's plain loads
// were default-cached.
// R14 = R13 verbatim + nontemporal weight loads.
#define KDIM 4096
#define NDIM 14336
#define MT_BYTES 65536            // xf bytes per m-tile (64 chunks * 1 KB)

typedef int v4i __attribute__((ext_vector_type(4)));

__device__ __forceinline__ int pack4(int w0, int w1, int w2, int w3) {
    int t01 = __builtin_amdgcn_perm(w1, w0, 0x00000400u);
    int t23 = __builtin_amdgcn_perm(w3, w2, 0x00000400u);
    return  __builtin_amdgcn_perm(t23, t01, 0x05040100u);
}

// Pack x [64,4096] int32 -> int8 in MFMA-fragment order (validated R8-R13):
// xf[mtile][chunk c][lane l][16B] = x[mtile*16+(l&15)][c*64+(l>>4)*16 ..+16].
__global__ void pack_x_frag_kernel(const int* __restrict__ xi, int8_t* __restrict__ xf) {
    const int o   = blockIdx.x * 256 + threadIdx.x;  // 0..16383
    const int mt  = o >> 12;
    const int rem = o & 4095;
    const int c   = rem >> 6;
    const int l   = rem & 63;
    const int r   = l & 15;
    const int kg  = l >> 4;
    const int* src = xi + ((size_t)(mt * 16 + r) * KDIM + c * 64 + kg * 16);
    v4i d;
    #pragma unroll
    for (int e = 0; e < 4; ++e) {
        v4i v = *(const v4i*)(src + e * 4);
        d[e] = pack4(v[0], v[1], v[2], v[3]);
    }
    *(v4i*)(xf + (size_t)o * 16) = d;
}

// Block = 8 waves (512 thr), one 16-wide N tile (16 weight rows).
// Phase A: wave w streams rows 2w, 2w+1 -- per row, 16 back-to-back 1 KB
//   contiguous NON-TEMPORAL loads (bypass cache insertion), in-register pack4,
//   swizzled ds_write into the 64 KB packed tile (<=2-way banks both sides).
// Phase B: wave w consumes chunks c=cc*4+(w&3) for m-tiles 2g,2g+1 (g=w>>2):
//   swizzled ds_read_b128 -> B-frag -> 2 MFMA.
// Epilogue: R9/R11-validated cross-wave split-K reduce.
// Fragment spec (HW-validated R2..R13): row/col = lane&15, k = (lane>>4)*16+j.
__global__ __launch_bounds__(512, 4) void gemm_i8_kernel(
    const int8_t* __restrict__ xf,
    const float*  __restrict__ xs,
    const int*    __restrict__ wq32,
    const float*  __restrict__ wscale,
    float*        __restrict__ out)
{
    __shared__ int8_t lds[65536];   // packed 16-row tile; epilogue aliases 16 KB

    const int tid  = threadIdx.x;
    const int wave = tid >> 6;     // 0..7
    const int lane = tid & 63;
    const int r    = lane & 15;
    const int kg   = lane >> 4;
    const int g    = wave >> 2;    // m-group: m-tiles 2g, 2g+1
    const int cw   = wave & 3;     // chunk class
    const int n0   = blockIdx.x * 16;

    // ---- Phase A: stream 2 whole rows sequentially, NON-TEMPORAL ----
    #pragma unroll
    for (int j = 0; j < 2; ++j) {
        const int R = 2 * wave + j;
        const int* src = wq32 + (size_t)(n0 + R) * KDIM + lane * 4;

        v4i gw[16];
        #pragma unroll
        for (int seg = 0; seg < 16; ++seg)
            gw[seg] = __builtin_nontemporal_load((const v4i*)(src + seg * 256));

        #pragma unroll
        for (int seg = 0; seg < 16; ++seg) {
            const int pk = pack4(gw[seg][0], gw[seg][1], gw[seg][2], gw[seg][3]);
            // original granule G = seg*16 + (lane>>2); low4 swizzled by ^R.
            const int gsw = ((lane >> 2) ^ R) & 15;
            const int dst = R * 4096 + ((seg * 16 + gsw) << 4) + ((lane & 3) << 2);
            *(int*)&lds[dst] = pk;
        }
    }

    __syncthreads();   // whole packed tile visible

    // ---- Phase B: 16 chunks per wave, fragment reads from LDS ----
    const int8_t* ap = xf + lane * 16;

    v4i acc[2];
    acc[0] = (v4i){0, 0, 0, 0};
    acc[1] = (v4i){0, 0, 0, 0};

    v4i ax[2];
    #pragma unroll
    for (int t = 0; t < 2; ++t)
        ax[t] = *(const v4i*)(ap + (size_t)(2 * g + t) * MT_BYTES + (size_t)cw * 1024);

    #pragma unroll
    for (int cc = 0; cc < 16; ++cc) {
        const int c = cc * 4 + cw;

        v4i axn[2];
        if (cc + 1 < 16) {
            const int cnext = (cc + 1) * 4 + cw;
            #pragma unroll
            for (int t = 0; t < 2; ++t)
                axn[t] = *(const v4i*)(ap + (size_t)(2 * g + t) * MT_BYTES
                                          + (size_t)cnext * 1024);
        }

        // B-fragment: row r, original granule gi = c*4+kg, swizzled low-4.
        const int gi = c * 4 + kg;
        const int gs = (gi & ~15) | ((gi & 15) ^ r);
        v4i b = *(const v4i*)&lds[r * 4096 + (gs << 4)];

        acc[0] = __builtin_amdgcn_mfma_i32_16x16x64_i8(ax[0], b, acc[0], 0, 0, 0);
        acc[1] = __builtin_amdgcn_mfma_i32_16x16x64_i8(ax[1], b, acc[1], 0, 0, 0);

        if (cc + 1 < 16) {
            ax[0] = axn[0];
            ax[1] = axn[1];
        }
    }

    // ---- Epilogue: cross-wave split-K reduce (validated R9/R11-R13) ----
    __syncthreads();
    int (*red)[2][256] = (int (*)[2][256])&lds[0];
    ((v4i*)red[wave][0])[lane] = acc[0];
    ((v4i*)red[wave][1])[lane] = acc[1];
    __syncthreads();

    if (wave < 4) {
        const int mt = wave;            // m-tile index 0..3
        const int gg = mt >> 1;
        const int tl = mt & 1;
        v4i t0 = ((v4i*)red[gg * 4 + 0][tl])[lane];
        v4i t1 = ((v4i*)red[gg * 4 + 1][tl])[lane];
        v4i t2 = ((v4i*)red[gg * 4 + 2][tl])[lane];
        v4i t3 = ((v4i*)red[gg * 4 + 3][tl])[lane];
        v4i tot = t0 + t1 + t2 + t3;

        // C/D layout (HW-validated R2): col = lane&15, row = (lane>>4)*4 + reg.
        const float scale = xs[0] * wscale[0];
        const int n = n0 + r;
        const int mbase = mt * 16 + kg * 4;
        #pragma unroll
        for (int i = 0; i < 4; ++i)
            out[(size_t)(mbase + i) * NDIM + n] = scale * (float)tot[i];
    }
}

extern "C" void kernel_launch(void* const* d_in, const int* in_sizes, int n_in,
                              void* d_out, int out_size, void* d_ws, size_t ws_size,
                              hipStream_t stream) {
    const int*   xq32   = (const int*)d_in[0];
    const float* xs     = (const float*)d_in[1];
    const int*   wq32   = (const int*)d_in[2];
    const float* wscale = (const float*)d_in[3];
    float* out = (float*)d_out;

    int8_t* xf = (int8_t*)d_ws;  // 256 KB fragment-ordered packed x

    pack_x_frag_kernel<<<64, 256, 0, stream>>>(xq32, xf);

    const int nblocks = NDIM / 16;  // 896
    gemm_i8_kernel<<<nblocks, 512, 0, stream>>>(xf, xs, wq32, wscale, out);
}